// Round 11
// baseline (46249.963 us; speedup 1.0000x reference)
//
#include <hip/hip_runtime.h>

#define DK 1024
#define NB 32768
#define BM 128
#define BN 128
#define BKT 32
#define RSF 144   // LDS row stride: 128 + 4-float gap per 32 cols (kills 4-way conflicts)

__device__ __forceinline__ int gcol(int c) { return c + ((c >> 5) << 2); }

// Reference model (probes r4-r8, verified r9/r10): np ref = f32 sgemm with
// KC=512 K-panels; per element ascending-k single-accumulator f32 FMA chain
// per panel; panel sums added in order (P0 + P1). DO NOT reorder.
// Two-pass split: PASS 0 = k in [0,512) -> raw partial into `out`;
//                 PASS 1 = k in [512,1024), tot = P0 + chn -> epilogue.
// MODE 0: y = x @ Pi^T (NT) -> idx (float)
// MODE 1: xhat = cent[idx] @ Pi (NN) -> resid = x - xhat
// MODE 2: p = resid @ S^T (NT) -> sign(p)
template<int MODE, int PASS>
__global__ __launch_bounds__(256, 4)
void gkp(const float* __restrict__ A,
         const float* __restrict__ W,
         const float* __restrict__ X,
         const float* __restrict__ cent,
         const float* __restrict__ bnd,
         float* __restrict__ out)
{
    __shared__ float As[BKT * RSF];
    __shared__ float Bs[BKT * RSF];
    __shared__ float centS[8];

    const int tid = threadIdx.x;
    const int tx8 = tid & 15, ty8 = tid >> 4;
    const int m0 = blockIdx.y * BM;
    const int n0 = blockIdx.x * BN;

    // A / NT-B staging: thread -> (row arow, 16-wide k range at ak0)
    const int arow  = tid >> 1;
    const int ak0   = (tid & 1) * 16;
    const int arowG = arow + ((arow >> 5) << 2);
    // NN-B staging (mode 1): thread -> (k-row brow, 16-wide col range bn0)
    const int brow = tid >> 3;
    const int bn0  = (tid & 7) * 16;

    if (MODE == 1 && tid < 8) centS[tid] = cent[tid];

    const int aoff = ty8 * 8 + ((ty8 >> 2) << 2);
    const int boff = tx8 * 8 + ((tx8 >> 2) << 2);

    float4 pa[4], pb[4];   // in-flight prefetch registers
    const int base = PASS * 16;   // k-tile offset of this pass

    auto load_tile = [&](int kt) {
        const int k0 = kt * BKT;
        const float* ap = &A[(size_t)(m0 + arow) * DK + k0 + ak0];
        pa[0] = *(const float4*)(ap + 0);
        pa[1] = *(const float4*)(ap + 4);
        pa[2] = *(const float4*)(ap + 8);
        pa[3] = *(const float4*)(ap + 12);
        if (MODE == 1) {
            const float* bp = &W[(size_t)(k0 + brow) * DK + n0 + bn0];
            pb[0] = *(const float4*)(bp + 0);
            pb[1] = *(const float4*)(bp + 4);
            pb[2] = *(const float4*)(bp + 8);
            pb[3] = *(const float4*)(bp + 12);
        } else {
            const float* bp = &W[(size_t)(n0 + arow) * DK + k0 + ak0];
            pb[0] = *(const float4*)(bp + 0);
            pb[1] = *(const float4*)(bp + 4);
            pb[2] = *(const float4*)(bp + 8);
            pb[3] = *(const float4*)(bp + 12);
        }
    };

    auto write_lds = [&]() {
        const float* pf = (const float*)pa;
        if (MODE == 1) {
#pragma unroll
            for (int e = 0; e < 16; ++e)
                As[(ak0 + e) * RSF + arowG] = centS[(int)pf[e]];
#pragma unroll
            for (int q = 0; q < 4; ++q)
                *(float4*)&Bs[brow * RSF + gcol(bn0 + q * 4)] = pb[q];
        } else {
#pragma unroll
            for (int e = 0; e < 16; ++e)
                As[(ak0 + e) * RSF + arowG] = pf[e];
            const float* qf = (const float*)pb;
#pragma unroll
            for (int e = 0; e < 16; ++e)
                Bs[(ak0 + e) * RSF + arowG] = qf[e];
        }
    };

    float chn[8][8];
#pragma unroll
    for (int i = 0; i < 8; ++i)
#pragma unroll
        for (int j = 0; j < 8; ++j) chn[i][j] = 0.0f;

    // prologue: stage first tile of this pass
    load_tile(base);
    __syncthreads();          // centS init visible (mode 1)
    write_lds();

    for (int kt = 0; kt < 16; ++kt) {
        if (kt + 1 < 16) load_tile(base + kt + 1);   // issue next loads early
        __syncthreads();                             // LDS writes visible

#pragma unroll
        for (int kk = 0; kk < BKT; ++kk) {
            float a[8], b[8];
            *(float4*)&a[0] = *(const float4*)&As[kk * RSF + aoff];
            *(float4*)&a[4] = *(const float4*)&As[kk * RSF + aoff + 4];
            *(float4*)&b[0] = *(const float4*)&Bs[kk * RSF + boff];
            *(float4*)&b[4] = *(const float4*)&Bs[kk * RSF + boff + 4];
#pragma unroll
            for (int i = 0; i < 8; ++i)
#pragma unroll
                for (int j = 0; j < 8; ++j)
                    chn[i][j] = fmaf(a[i], b[j], chn[i][j]);
        }

        __syncthreads();                             // all reads done
        if (kt + 1 < 16) write_lds();                // park prefetched tile
    }

    // ---- epilogue ----
    if constexpr (PASS == 0) {
        // raw panel-0 sums to out (same thread re-reads them in pass 1)
#pragma unroll
        for (int i = 0; i < 8; ++i) {
            const int row = m0 + ty8 * 8 + i;
#pragma unroll
            for (int jq = 0; jq < 2; ++jq) {
                float4 v;
                v.x = chn[i][jq * 4 + 0];
                v.y = chn[i][jq * 4 + 1];
                v.z = chn[i][jq * 4 + 2];
                v.w = chn[i][jq * 4 + 3];
                *(float4*)&out[(size_t)row * DK + n0 + tx8 * 8 + jq * 4] = v;
            }
        }
    } else if constexpr (MODE == 0) {
        float bb[7];
#pragma unroll
        for (int t = 0; t < 7; ++t) bb[t] = bnd[t];
#pragma unroll
        for (int i = 0; i < 8; ++i) {
            const int row = m0 + ty8 * 8 + i;
#pragma unroll
            for (int jq = 0; jq < 2; ++jq) {
                const int col = n0 + tx8 * 8 + jq * 4;
                const float4 p = *(const float4*)&out[(size_t)row * DK + col];
                float4 v;
#pragma unroll
                for (int e = 0; e < 4; ++e) {
                    const float yf = ((const float*)&p)[e] + chn[i][jq * 4 + e];
                    int id = 0;
#pragma unroll
                    for (int t = 0; t < 7; ++t) id += (yf > bb[t]) ? 1 : 0;
                    ((float*)&v)[e] = (float)id;
                }
                *(float4*)&out[(size_t)row * DK + col] = v;
            }
        }
    } else if constexpr (MODE == 1) {
#pragma unroll
        for (int i = 0; i < 8; ++i) {
            const int row = m0 + ty8 * 8 + i;
#pragma unroll
            for (int jq = 0; jq < 2; ++jq) {
                const int col = n0 + tx8 * 8 + jq * 4;
                const float4 p  = *(const float4*)&out[(size_t)row * DK + col];
                const float4 xv = *(const float4*)&X[(size_t)row * DK + col];
                float4 v;
                v.x = xv.x - (p.x + chn[i][jq * 4 + 0]);
                v.y = xv.y - (p.y + chn[i][jq * 4 + 1]);
                v.z = xv.z - (p.z + chn[i][jq * 4 + 2]);
                v.w = xv.w - (p.w + chn[i][jq * 4 + 3]);
                *(float4*)&out[(size_t)row * DK + col] = v;
            }
        }
    } else {
#pragma unroll
        for (int i = 0; i < 8; ++i) {
            const int row = m0 + ty8 * 8 + i;
#pragma unroll
            for (int jq = 0; jq < 2; ++jq) {
                const int col = n0 + tx8 * 8 + jq * 4;
                const float4 p = *(const float4*)&out[(size_t)row * DK + col];
                float4 v;
#pragma unroll
                for (int e = 0; e < 4; ++e)
                    ((float*)&v)[e] =
                        ((((const float*)&p)[e] + chn[i][jq * 4 + e]) >= 0.0f)
                            ? 1.0f : -1.0f;
                *(float4*)&out[(size_t)row * DK + col] = v;
            }
        }
    }
}

__global__ __launch_bounds__(256)
void norm_k(const float* __restrict__ resid, float* __restrict__ outn)
{
    const int lane = threadIdx.x & 63;
    const int row  = blockIdx.x * 4 + (threadIdx.x >> 6);
    const float* r = &resid[(size_t)row * DK];
    double s = 0.0;
    for (int i = lane; i < DK; i += 64) {
        const double v = (double)r[i];
        s += v * v;
    }
#pragma unroll
    for (int off = 32; off > 0; off >>= 1)
        s += __shfl_xor(s, off, 64);
    if (lane == 0) outn[row] = (float)sqrt(s);
}

// Fallback (small ws): residual parked in out_sign; each block owns a 16-row
// band, preloads it to LDS (race-free in-place), emits norms + signs.
__global__ __launch_bounds__(256)
void stage2_band(const float* __restrict__ RS,
                 const float* __restrict__ Sm,
                 float* __restrict__ out_sign,
                 float* __restrict__ out_norm)
{
    __shared__ float Rs[16][DK + 1];
    __shared__ float Bsh[16][64];

    const int tid = threadIdx.x;
    const int m0  = blockIdx.x * 16;

    for (int c = tid; c < 16 * 256; c += 256) {
        const int row = c >> 8, q = c & 255;
        const float4 v = *(const float4*)&RS[(size_t)(m0 + row) * DK + q * 4];
        Rs[row][q * 4 + 0] = v.x;
        Rs[row][q * 4 + 1] = v.y;
        Rs[row][q * 4 + 2] = v.z;
        Rs[row][q * 4 + 3] = v.w;
    }
    __syncthreads();

    {
        const int row = tid >> 4, sub = tid & 15;
        double s = 0.0;
        for (int c = sub; c < DK; c += 16) {
            const double v = (double)Rs[row][c];
            s += v * v;
        }
        s += __shfl_xor(s, 1, 16);
        s += __shfl_xor(s, 2, 16);
        s += __shfl_xor(s, 4, 16);
        s += __shfl_xor(s, 8, 16);
        if (sub == 0) out_norm[m0 + row] = (float)sqrt(s);
    }

    const int tx = tid & 15, ty = tid >> 4;
    const int srow = tid >> 2, s4 = tid & 3;

    for (int nt = 0; nt < 16; ++nt) {
        const int n0 = nt * 64;
        float chn[4] = {0.f, 0.f, 0.f, 0.f}, tot[4] = {0.f, 0.f, 0.f, 0.f};

        for (int kt = 0; kt < 64; ++kt) {
            const int k0 = kt * 16;
            __syncthreads();
            const float4 w = *(const float4*)&Sm[(size_t)(n0 + srow) * DK + k0 + s4 * 4];
            Bsh[s4 * 4 + 0][srow] = w.x;
            Bsh[s4 * 4 + 1][srow] = w.y;
            Bsh[s4 * 4 + 2][srow] = w.z;
            Bsh[s4 * 4 + 3][srow] = w.w;
            __syncthreads();
#pragma unroll
            for (int kk = 0; kk < 16; ++kk) {
                const float a = Rs[ty][k0 + kk];
#pragma unroll
                for (int j = 0; j < 4; ++j)
                    chn[j] = fmaf(a, Bsh[kk][tx * 4 + j], chn[j]);
            }
            if (kt == 31) {   // k=512 panel boundary
#pragma unroll
                for (int j = 0; j < 4; ++j) { tot[j] += chn[j]; chn[j] = 0.0f; }
            }
        }
#pragma unroll
        for (int j = 0; j < 4; ++j) tot[j] += chn[j];
#pragma unroll
        for (int j = 0; j < 4; ++j)
            out_sign[(size_t)(m0 + ty) * DK + n0 + tx * 4 + j] =
                (tot[j] >= 0.0f) ? 1.0f : -1.0f;
    }
}

extern "C" void kernel_launch(void* const* d_in, const int* in_sizes, int n_in,
                              void* d_out, int out_size, void* d_ws, size_t ws_size,
                              hipStream_t stream)
{
    const float* x    = (const float*)d_in[0];
    const float* Pi   = (const float*)d_in[1];
    const float* S    = (const float*)d_in[2];
    const float* cent = (const float*)d_in[3];
    const float* bnd  = (const float*)d_in[4];

    float* out_idx  = (float*)d_out;
    float* out_sign = out_idx + (size_t)NB * DK;
    float* out_norm = out_idx + 2 * (size_t)NB * DK;

    const dim3 grid(DK / BN, NB / BM);      // (8, 256)
    const size_t needF32 = (size_t)NB * DK * sizeof(float);   // 134 MB

    gkp<0, 0><<<grid, 256, 0, stream>>>(x, Pi, (const float*)nullptr, cent, bnd, out_idx);
    gkp<0, 1><<<grid, 256, 0, stream>>>(x, Pi, (const float*)nullptr, cent, bnd, out_idx);

    if (ws_size >= needF32) {
        float* resid = (float*)d_ws;
        gkp<1, 0><<<grid, 256, 0, stream>>>(out_idx, Pi, x, cent, bnd, resid);
        gkp<1, 1><<<grid, 256, 0, stream>>>(out_idx, Pi, x, cent, bnd, resid);
        gkp<2, 0><<<grid, 256, 0, stream>>>(resid, S, (const float*)nullptr, cent, bnd, out_sign);
        gkp<2, 1><<<grid, 256, 0, stream>>>(resid, S, (const float*)nullptr, cent, bnd, out_sign);
        norm_k<<<NB / 4, 256, 0, stream>>>(resid, out_norm);
    } else {
        gkp<1, 0><<<grid, 256, 0, stream>>>(out_idx, Pi, x, cent, bnd, out_sign);
        gkp<1, 1><<<grid, 256, 0, stream>>>(out_idx, Pi, x, cent, bnd, out_sign);
        stage2_band<<<NB / 16, 256, 0, stream>>>(out_sign, S, out_sign, out_norm);
    }
}

// Round 12
// 26395.410 us; speedup vs baseline: 1.7522x; 1.7522x over previous
//
#include <hip/hip_runtime.h>

#define DK 1024
#define NB 32768
#define BM 128
#define BN 128
#define BKT 32
#define RSF 144   // LDS row stride: 128 + 4-float gap per 32 cols (kills 4-way conflicts)

__device__ __forceinline__ int gcol(int c) { return c + ((c >> 5) << 2); }

// Reference model (probes r4-r8, verified r9/r10/r11): np ref = f32 sgemm with
// KC=512 K-panels; per element ascending-k single-accumulator f32 FMA chain
// per panel; panel sums added in order (P0 + P1). DO NOT reorder.
// Two-pass split: PASS 0 = k in [0,512) -> raw partial into `out`;
//                 PASS 1 = k in [512,1024), tot = P0 + chn -> epilogue.
// MODE 0: y = x @ Pi^T (NT) -> idx (float)
// MODE 1: xhat = cent[idx] @ Pi (NN) -> resid = x - xhat
// MODE 2: p = resid @ S^T (NT) -> sign(p)
//
// NOTE on occupancy knobs (r11 lesson): __launch_bounds__(256,4) made regalloc
// chase max occupancy -> 64 VGPR + full accumulator spill -> 30 GB/dispatch of
// scratch traffic (13x slowdown). Use waves_per_eu(2,4): max=4 sets a 128-VGPR
// target (live set ~115 fits, no spill), min=2 is non-binding.
template<int MODE, int PASS>
__global__ __launch_bounds__(256)
__attribute__((amdgpu_waves_per_eu(2, 4)))
void gkp(const float* __restrict__ A,
         const float* __restrict__ W,
         const float* __restrict__ X,
         const float* __restrict__ cent,
         const float* __restrict__ bnd,
         float* __restrict__ out)
{
    __shared__ float As[BKT * RSF];
    __shared__ float Bs[BKT * RSF];
    __shared__ float centS[8];

    const int tid = threadIdx.x;
    const int tx8 = tid & 15, ty8 = tid >> 4;
    const int m0 = blockIdx.y * BM;
    const int n0 = blockIdx.x * BN;

    // A / NT-B staging: thread -> (row arow, 16-wide k range at ak0)
    const int arow  = tid >> 1;
    const int ak0   = (tid & 1) * 16;
    const int arowG = arow + ((arow >> 5) << 2);
    // NN-B staging (mode 1): thread -> (k-row brow, 16-wide col range bn0)
    const int brow = tid >> 3;
    const int bn0  = (tid & 7) * 16;

    if (MODE == 1 && tid < 8) centS[tid] = cent[tid];

    const int aoff = ty8 * 8 + ((ty8 >> 2) << 2);
    const int boff = tx8 * 8 + ((tx8 >> 2) << 2);

    float4 pa[4], pb[4];   // in-flight prefetch registers
    const int base = PASS * 16;   // k-tile offset of this pass

    auto load_tile = [&](int kt) {
        const int k0 = kt * BKT;
        const float* ap = &A[(size_t)(m0 + arow) * DK + k0 + ak0];
        pa[0] = *(const float4*)(ap + 0);
        pa[1] = *(const float4*)(ap + 4);
        pa[2] = *(const float4*)(ap + 8);
        pa[3] = *(const float4*)(ap + 12);
        if (MODE == 1) {
            const float* bp = &W[(size_t)(k0 + brow) * DK + n0 + bn0];
            pb[0] = *(const float4*)(bp + 0);
            pb[1] = *(const float4*)(bp + 4);
            pb[2] = *(const float4*)(bp + 8);
            pb[3] = *(const float4*)(bp + 12);
        } else {
            const float* bp = &W[(size_t)(n0 + arow) * DK + k0 + ak0];
            pb[0] = *(const float4*)(bp + 0);
            pb[1] = *(const float4*)(bp + 4);
            pb[2] = *(const float4*)(bp + 8);
            pb[3] = *(const float4*)(bp + 12);
        }
    };

    auto write_lds = [&]() {
        const float* pf = (const float*)pa;
        if (MODE == 1) {
#pragma unroll
            for (int e = 0; e < 16; ++e)
                As[(ak0 + e) * RSF + arowG] = centS[(int)pf[e]];
#pragma unroll
            for (int q = 0; q < 4; ++q)
                *(float4*)&Bs[brow * RSF + gcol(bn0 + q * 4)] = pb[q];
        } else {
#pragma unroll
            for (int e = 0; e < 16; ++e)
                As[(ak0 + e) * RSF + arowG] = pf[e];
            const float* qf = (const float*)pb;
#pragma unroll
            for (int e = 0; e < 16; ++e)
                Bs[(ak0 + e) * RSF + arowG] = qf[e];
        }
    };

    float chn[8][8];
#pragma unroll
    for (int i = 0; i < 8; ++i)
#pragma unroll
        for (int j = 0; j < 8; ++j) chn[i][j] = 0.0f;

    // prologue: stage first tile of this pass
    load_tile(base);
    __syncthreads();          // centS init visible (mode 1)
    write_lds();

    for (int kt = 0; kt < 16; ++kt) {
        if (kt + 1 < 16) load_tile(base + kt + 1);   // issue next loads early
        __syncthreads();                             // LDS writes visible

#pragma unroll
        for (int kk = 0; kk < BKT; ++kk) {
            float a[8], b[8];
            *(float4*)&a[0] = *(const float4*)&As[kk * RSF + aoff];
            *(float4*)&a[4] = *(const float4*)&As[kk * RSF + aoff + 4];
            *(float4*)&b[0] = *(const float4*)&Bs[kk * RSF + boff];
            *(float4*)&b[4] = *(const float4*)&Bs[kk * RSF + boff + 4];
#pragma unroll
            for (int i = 0; i < 8; ++i)
#pragma unroll
                for (int j = 0; j < 8; ++j)
                    chn[i][j] = fmaf(a[i], b[j], chn[i][j]);
        }

        __syncthreads();                             // all reads done
        if (kt + 1 < 16) write_lds();                // park prefetched tile
    }

    // ---- epilogue ----
    if constexpr (PASS == 0) {
        // raw panel-0 sums to out (same thread re-reads them in pass 1)
#pragma unroll
        for (int i = 0; i < 8; ++i) {
            const int row = m0 + ty8 * 8 + i;
#pragma unroll
            for (int jq = 0; jq < 2; ++jq) {
                float4 v;
                v.x = chn[i][jq * 4 + 0];
                v.y = chn[i][jq * 4 + 1];
                v.z = chn[i][jq * 4 + 2];
                v.w = chn[i][jq * 4 + 3];
                *(float4*)&out[(size_t)row * DK + n0 + tx8 * 8 + jq * 4] = v;
            }
        }
    } else if constexpr (MODE == 0) {
        float bb[7];
#pragma unroll
        for (int t = 0; t < 7; ++t) bb[t] = bnd[t];
#pragma unroll
        for (int i = 0; i < 8; ++i) {
            const int row = m0 + ty8 * 8 + i;
#pragma unroll
            for (int jq = 0; jq < 2; ++jq) {
                const int col = n0 + tx8 * 8 + jq * 4;
                const float4 p = *(const float4*)&out[(size_t)row * DK + col];
                float4 v;
#pragma unroll
                for (int e = 0; e < 4; ++e) {
                    const float yf = ((const float*)&p)[e] + chn[i][jq * 4 + e];
                    int id = 0;
#pragma unroll
                    for (int t = 0; t < 7; ++t) id += (yf > bb[t]) ? 1 : 0;
                    ((float*)&v)[e] = (float)id;
                }
                *(float4*)&out[(size_t)row * DK + col] = v;
            }
        }
    } else if constexpr (MODE == 1) {
#pragma unroll
        for (int i = 0; i < 8; ++i) {
            const int row = m0 + ty8 * 8 + i;
#pragma unroll
            for (int jq = 0; jq < 2; ++jq) {
                const int col = n0 + tx8 * 8 + jq * 4;
                const float4 p  = *(const float4*)&out[(size_t)row * DK + col];
                const float4 xv = *(const float4*)&X[(size_t)row * DK + col];
                float4 v;
                v.x = xv.x - (p.x + chn[i][jq * 4 + 0]);
                v.y = xv.y - (p.y + chn[i][jq * 4 + 1]);
                v.z = xv.z - (p.z + chn[i][jq * 4 + 2]);
                v.w = xv.w - (p.w + chn[i][jq * 4 + 3]);
                *(float4*)&out[(size_t)row * DK + col] = v;
            }
        }
    } else {
#pragma unroll
        for (int i = 0; i < 8; ++i) {
            const int row = m0 + ty8 * 8 + i;
#pragma unroll
            for (int jq = 0; jq < 2; ++jq) {
                const int col = n0 + tx8 * 8 + jq * 4;
                const float4 p = *(const float4*)&out[(size_t)row * DK + col];
                float4 v;
#pragma unroll
                for (int e = 0; e < 4; ++e)
                    ((float*)&v)[e] =
                        ((((const float*)&p)[e] + chn[i][jq * 4 + e]) >= 0.0f)
                            ? 1.0f : -1.0f;
                *(float4*)&out[(size_t)row * DK + col] = v;
            }
        }
    }
}

__global__ __launch_bounds__(256)
void norm_k(const float* __restrict__ resid, float* __restrict__ outn)
{
    const int lane = threadIdx.x & 63;
    const int row  = blockIdx.x * 4 + (threadIdx.x >> 6);
    const float* r = &resid[(size_t)row * DK];
    double s = 0.0;
    for (int i = lane; i < DK; i += 64) {
        const double v = (double)r[i];
        s += v * v;
    }
#pragma unroll
    for (int off = 32; off > 0; off >>= 1)
        s += __shfl_xor(s, off, 64);
    if (lane == 0) outn[row] = (float)sqrt(s);
}

// Fallback (small ws): residual parked in out_sign; each block owns a 16-row
// band, preloads it to LDS (race-free in-place), emits norms + signs.
__global__ __launch_bounds__(256)
void stage2_band(const float* __restrict__ RS,
                 const float* __restrict__ Sm,
                 float* __restrict__ out_sign,
                 float* __restrict__ out_norm)
{
    __shared__ float Rs[16][DK + 1];
    __shared__ float Bsh[16][64];

    const int tid = threadIdx.x;
    const int m0  = blockIdx.x * 16;

    for (int c = tid; c < 16 * 256; c += 256) {
        const int row = c >> 8, q = c & 255;
        const float4 v = *(const float4*)&RS[(size_t)(m0 + row) * DK + q * 4];
        Rs[row][q * 4 + 0] = v.x;
        Rs[row][q * 4 + 1] = v.y;
        Rs[row][q * 4 + 2] = v.z;
        Rs[row][q * 4 + 3] = v.w;
    }
    __syncthreads();

    {
        const int row = tid >> 4, sub = tid & 15;
        double s = 0.0;
        for (int c = sub; c < DK; c += 16) {
            const double v = (double)Rs[row][c];
            s += v * v;
        }
        s += __shfl_xor(s, 1, 16);
        s += __shfl_xor(s, 2, 16);
        s += __shfl_xor(s, 4, 16);
        s += __shfl_xor(s, 8, 16);
        if (sub == 0) out_norm[m0 + row] = (float)sqrt(s);
    }

    const int tx = tid & 15, ty = tid >> 4;
    const int srow = tid >> 2, s4 = tid & 3;

    for (int nt = 0; nt < 16; ++nt) {
        const int n0 = nt * 64;
        float chn[4] = {0.f, 0.f, 0.f, 0.f}, tot[4] = {0.f, 0.f, 0.f, 0.f};

        for (int kt = 0; kt < 64; ++kt) {
            const int k0 = kt * 16;
            __syncthreads();
            const float4 w = *(const float4*)&Sm[(size_t)(n0 + srow) * DK + k0 + s4 * 4];
            Bsh[s4 * 4 + 0][srow] = w.x;
            Bsh[s4 * 4 + 1][srow] = w.y;
            Bsh[s4 * 4 + 2][srow] = w.z;
            Bsh[s4 * 4 + 3][srow] = w.w;
            __syncthreads();
#pragma unroll
            for (int kk = 0; kk < 16; ++kk) {
                const float a = Rs[ty][k0 + kk];
#pragma unroll
                for (int j = 0; j < 4; ++j)
                    chn[j] = fmaf(a, Bsh[kk][tx * 4 + j], chn[j]);
            }
            if (kt == 31) {   // k=512 panel boundary
#pragma unroll
                for (int j = 0; j < 4; ++j) { tot[j] += chn[j]; chn[j] = 0.0f; }
            }
        }
#pragma unroll
        for (int j = 0; j < 4; ++j) tot[j] += chn[j];
#pragma unroll
        for (int j = 0; j < 4; ++j)
            out_sign[(size_t)(m0 + ty) * DK + n0 + tx * 4 + j] =
                (tot[j] >= 0.0f) ? 1.0f : -1.0f;
    }
}

extern "C" void kernel_launch(void* const* d_in, const int* in_sizes, int n_in,
                              void* d_out, int out_size, void* d_ws, size_t ws_size,
                              hipStream_t stream)
{
    const float* x    = (const float*)d_in[0];
    const float* Pi   = (const float*)d_in[1];
    const float* S    = (const float*)d_in[2];
    const float* cent = (const float*)d_in[3];
    const float* bnd  = (const float*)d_in[4];

    float* out_idx  = (float*)d_out;
    float* out_sign = out_idx + (size_t)NB * DK;
    float* out_norm = out_idx + 2 * (size_t)NB * DK;

    const dim3 grid(DK / BN, NB / BM);      // (8, 256)
    const size_t needF32 = (size_t)NB * DK * sizeof(float);   // 134 MB

    gkp<0, 0><<<grid, 256, 0, stream>>>(x, Pi, (const float*)nullptr, cent, bnd, out_idx);
    gkp<0, 1><<<grid, 256, 0, stream>>>(x, Pi, (const float*)nullptr, cent, bnd, out_idx);

    if (ws_size >= needF32) {
        float* resid = (float*)d_ws;
        gkp<1, 0><<<grid, 256, 0, stream>>>(out_idx, Pi, x, cent, bnd, resid);
        gkp<1, 1><<<grid, 256, 0, stream>>>(out_idx, Pi, x, cent, bnd, resid);
        gkp<2, 0><<<grid, 256, 0, stream>>>(resid, S, (const float*)nullptr, cent, bnd, out_sign);
        gkp<2, 1><<<grid, 256, 0, stream>>>(resid, S, (const float*)nullptr, cent, bnd, out_sign);
        norm_k<<<NB / 4, 256, 0, stream>>>(resid, out_norm);
    } else {
        gkp<1, 0><<<grid, 256, 0, stream>>>(out_idx, Pi, x, cent, bnd, out_sign);
        gkp<1, 1><<<grid, 256, 0, stream>>>(out_idx, Pi, x, cent, bnd, out_sign);
        stage2_band<<<NB / 16, 256, 0, stream>>>(out_sign, S, out_sign, out_norm);
    }
}

// Round 13
// 3383.084 us; speedup vs baseline: 13.6709x; 7.8022x over previous
//
#include <hip/hip_runtime.h>

#define DK 1024
#define NB 32768
#define BM 128
#define BN 128
#define BKT 32
#define NKT (DK / BKT)     // 32 k-tiles
#define FLUSH_KT 15        // KC=512 panel boundary (after kt 15)

typedef const __attribute__((address_space(1))) void GAS;
typedef __attribute__((address_space(3))) void LAS;

__device__ __forceinline__ void gll16(const void* g, void* l) {
    __builtin_amdgcn_global_load_lds((GAS*)g, (LAS*)l, 16, 0, 0);
}

// Reference model (probes r4-r8, verified r9-r12): np ref = f32 sgemm, KC=512
// K-panels; per element ascending-k single-accumulator f32 FMA chain per
// panel; panel sums added in order (P0 + P1). DO NOT reorder the chain.
// tot is eliminated: at kt==FLUSH_KT raw P0 is flushed to `out` and re-read
// in the epilogue (same thread, in-order add -> bit-identical).
// LDS layout: [row][32 k-floats], granule (4-float) slot = g ^ ((row>>3)&7).
// NT tiles staged via global_load_lds with pre-swizzled SOURCE addresses
// (dest linear, m173 pattern). NN B (mode 1) staged linear, no swizzle.
// MODE 0: y = x @ Pi^T (NT) -> idx (float)
// MODE 1: xhat = cent[idx] @ Pi (NN) -> resid = x - xhat
// MODE 2: p = resid @ S^T (NT) -> sign(p)
template<int MODE>
__global__ __launch_bounds__(256)
void gk(const float* __restrict__ A,
        const float* __restrict__ W,
        const float* __restrict__ X,
        const float* __restrict__ cent,
        const float* __restrict__ bnd,
        float* __restrict__ out)
{
    __shared__ float As[2][BM * BKT];
    __shared__ float Bs[2][BN * BKT];
    __shared__ float centS[8];

    const int tid  = threadIdx.x;
    const int lane = tid & 63;
    const int wid  = tid >> 6;
    const int tx8 = tid & 15, ty8 = tid >> 4;
    const int m0 = blockIdx.y * BM;
    const int n0 = blockIdx.x * BN;

    const int lr = lane >> 3;       // local row within 8-row DMA chunk
    const int gs = lane & 7;        // granule slot within row

    // mode-1 manual A staging coords
    const int arow = tid >> 1;            // 0..127
    const int ah   = (tid & 1) * 4;       // granule base 0 or 4
    const int akey = (arow >> 3) & 7;
    float4 pidx[4];

    if (MODE == 1 && tid < 8) centS[tid] = cent[tid];

    // NT tile DMA: 16 instrs/block; wave w instr q stages rows w*32+q*8..+7.
    auto stageNT = [&](float* dst, const float* src, int rowbase, int kt) {
#pragma unroll
        for (int q = 0; q < 4; ++q) {
            const int rb  = wid * 32 + q * 8;
            const int key = (rb >> 3) & 7;                 // wave-uniform
            const float* gp = src + (size_t)(rowbase + rb + lr) * DK
                                  + kt * BKT + ((gs ^ key) << 2);
            gll16(gp, dst + rb * BKT);
        }
    };
    // NN B tile DMA (mode 1): Bs[kk][n], linear; 2 kk-rows per instr.
    auto stageNN = [&](float* dst, const float* src, int kt) {
#pragma unroll
        for (int q = 0; q < 4; ++q) {
            const int r2 = (wid * 4 + q) * 2;
            const float* gp = src + (size_t)(kt * BKT + r2 + (lane >> 5)) * DK
                                  + n0 + ((lane & 31) << 2);
            gll16(gp, dst + r2 * BN);
        }
    };
    auto loadIdx = [&](int kt) {
#pragma unroll
        for (int g = 0; g < 4; ++g)
            pidx[g] = *(const float4*)&A[(size_t)(m0 + arow) * DK + kt * BKT + (ah + g) * 4];
    };
    auto writeA = [&](float* dst) {
#pragma unroll
        for (int g = 0; g < 4; ++g) {
            float4 v;
            v.x = centS[(int)pidx[g].x];
            v.y = centS[(int)pidx[g].y];
            v.z = centS[(int)pidx[g].z];
            v.w = centS[(int)pidx[g].w];
            *(float4*)&dst[arow * BKT + (((ah + g) ^ akey) << 2)] = v;
        }
    };

    float chn[8][8];
#pragma unroll
    for (int i = 0; i < 8; ++i)
#pragma unroll
        for (int j = 0; j < 8; ++j) chn[i][j] = 0.0f;

    const int akr = ty8 & 7;   // read-side XOR keys: rows ty8*8+i -> (row>>3)=ty8
    const int bkr = tx8 & 7;

    // ---- prologue: stage tile 0 ----
    if (MODE == 1) { loadIdx(0); stageNN(Bs[0], W, 0); }
    else           { stageNT(As[0], A, m0, 0); stageNT(Bs[0], W, n0, 0); }
    __syncthreads();                      // drains DMA; centS visible
    if (MODE == 1) { writeA(As[0]); __syncthreads(); }

    int cur = 0;
    for (int kt = 0; kt < NKT; ++kt) {
        // issue next tile's staging BEFORE compute (flight hides under compute)
        if (kt + 1 < NKT) {
            if (MODE == 1) { loadIdx(kt + 1); stageNN(Bs[cur ^ 1], W, kt + 1); }
            else { stageNT(As[cur ^ 1], A, m0, kt + 1);
                   stageNT(Bs[cur ^ 1], W, n0, kt + 1); }
        }

        // ---- compute tile kt (ascending k, single accumulator) ----
        const float4* As4 = (const float4*)As[cur];
        const float4* Bs4 = (const float4*)Bs[cur];
#pragma unroll
        for (int c = 0; c < 8; ++c) {
            float4 a4[8];
#pragma unroll
            for (int i = 0; i < 8; ++i)
                a4[i] = As4[(ty8 * 8 + i) * 8 + (c ^ akr)];
            if constexpr (MODE != 1) {
                float4 b4[8];
#pragma unroll
                for (int j = 0; j < 8; ++j)
                    b4[j] = Bs4[(tx8 * 8 + j) * 8 + (c ^ bkr)];
#pragma unroll
                for (int e = 0; e < 4; ++e)
#pragma unroll
                    for (int i = 0; i < 8; ++i)
#pragma unroll
                        for (int j = 0; j < 8; ++j)
                            chn[i][j] = fmaf(((const float*)&a4[i])[e],
                                             ((const float*)&b4[j])[e], chn[i][j]);
            } else {
#pragma unroll
                for (int e = 0; e < 4; ++e) {
                    const float4 b0 = *(const float4*)&Bs[cur][(c * 4 + e) * BN + tx8 * 8];
                    const float4 b1 = *(const float4*)&Bs[cur][(c * 4 + e) * BN + tx8 * 8 + 4];
                    const float b[8] = {b0.x, b0.y, b0.z, b0.w, b1.x, b1.y, b1.z, b1.w};
#pragma unroll
                    for (int i = 0; i < 8; ++i)
#pragma unroll
                        for (int j = 0; j < 8; ++j)
                            chn[i][j] = fmaf(((const float*)&a4[i])[e], b[j], chn[i][j]);
                }
            }
        }

        // ---- KC=512 panel flush: park P0 in out, restart chain ----
        if (kt == FLUSH_KT) {
#pragma unroll
            for (int i = 0; i < 8; ++i) {
                const int row = m0 + ty8 * 8 + i;
#pragma unroll
                for (int jq = 0; jq < 2; ++jq) {
                    float4 v;
                    v.x = chn[i][jq * 4 + 0];
                    v.y = chn[i][jq * 4 + 1];
                    v.z = chn[i][jq * 4 + 2];
                    v.w = chn[i][jq * 4 + 3];
                    *(float4*)&out[(size_t)row * DK + n0 + tx8 * 8 + jq * 4] = v;
                    chn[i][jq * 4 + 0] = 0.0f;
                    chn[i][jq * 4 + 1] = 0.0f;
                    chn[i][jq * 4 + 2] = 0.0f;
                    chn[i][jq * 4 + 3] = 0.0f;
                }
            }
        }

        if (MODE == 1 && kt + 1 < NKT) writeA(As[cur ^ 1]);  // after compute, pre-barrier
        __syncthreads();     // drains DMA + ds_writes; next buffer ready
        cur ^= 1;
    }

    // ---- epilogue: tot = P0(from out) + P1(chn), in order ----
    if constexpr (MODE == 0) {
        float bb[7];
#pragma unroll
        for (int t = 0; t < 7; ++t) bb[t] = bnd[t];
#pragma unroll
        for (int i = 0; i < 8; ++i) {
            const int row = m0 + ty8 * 8 + i;
#pragma unroll
            for (int jq = 0; jq < 2; ++jq) {
                const int col = n0 + tx8 * 8 + jq * 4;
                const float4 p = *(const float4*)&out[(size_t)row * DK + col];
                float4 v;
#pragma unroll
                for (int e = 0; e < 4; ++e) {
                    const float yf = ((const float*)&p)[e] + chn[i][jq * 4 + e];
                    int id = 0;
#pragma unroll
                    for (int t = 0; t < 7; ++t) id += (yf > bb[t]) ? 1 : 0;
                    ((float*)&v)[e] = (float)id;
                }
                *(float4*)&out[(size_t)row * DK + col] = v;
            }
        }
    } else if constexpr (MODE == 1) {
#pragma unroll
        for (int i = 0; i < 8; ++i) {
            const int row = m0 + ty8 * 8 + i;
#pragma unroll
            for (int jq = 0; jq < 2; ++jq) {
                const int col = n0 + tx8 * 8 + jq * 4;
                const float4 p  = *(const float4*)&out[(size_t)row * DK + col];
                const float4 xv = *(const float4*)&X[(size_t)row * DK + col];
                float4 v;
                v.x = xv.x - (p.x + chn[i][jq * 4 + 0]);
                v.y = xv.y - (p.y + chn[i][jq * 4 + 1]);
                v.z = xv.z - (p.z + chn[i][jq * 4 + 2]);
                v.w = xv.w - (p.w + chn[i][jq * 4 + 3]);
                *(float4*)&out[(size_t)row * DK + col] = v;
            }
        }
    } else {
#pragma unroll
        for (int i = 0; i < 8; ++i) {
            const int row = m0 + ty8 * 8 + i;
#pragma unroll
            for (int jq = 0; jq < 2; ++jq) {
                const int col = n0 + tx8 * 8 + jq * 4;
                const float4 p = *(const float4*)&out[(size_t)row * DK + col];
                float4 v;
#pragma unroll
                for (int e = 0; e < 4; ++e)
                    ((float*)&v)[e] =
                        ((((const float*)&p)[e] + chn[i][jq * 4 + e]) >= 0.0f)
                            ? 1.0f : -1.0f;
                *(float4*)&out[(size_t)row * DK + col] = v;
            }
        }
    }
}

__global__ __launch_bounds__(256)
void norm_k(const float* __restrict__ resid, float* __restrict__ outn)
{
    const int lane = threadIdx.x & 63;
    const int row  = blockIdx.x * 4 + (threadIdx.x >> 6);
    const float* r = &resid[(size_t)row * DK];
    double s = 0.0;
    for (int i = lane; i < DK; i += 64) {
        const double v = (double)r[i];
        s += v * v;
    }
#pragma unroll
    for (int off = 32; off > 0; off >>= 1)
        s += __shfl_xor(s, off, 64);
    if (lane == 0) outn[row] = (float)sqrt(s);
}

// Fallback (small ws): residual parked in out_sign; band kernel emits norms+signs.
__global__ __launch_bounds__(256)
void stage2_band(const float* __restrict__ RS,
                 const float* __restrict__ Sm,
                 float* __restrict__ out_sign,
                 float* __restrict__ out_norm)
{
    __shared__ float Rs[16][DK + 1];
    __shared__ float Bsh[16][64];

    const int tid = threadIdx.x;
    const int m0  = blockIdx.x * 16;

    for (int c = tid; c < 16 * 256; c += 256) {
        const int row = c >> 8, q = c & 255;
        const float4 v = *(const float4*)&RS[(size_t)(m0 + row) * DK + q * 4];
        Rs[row][q * 4 + 0] = v.x;
        Rs[row][q * 4 + 1] = v.y;
        Rs[row][q * 4 + 2] = v.z;
        Rs[row][q * 4 + 3] = v.w;
    }
    __syncthreads();

    {
        const int row = tid >> 4, sub = tid & 15;
        double s = 0.0;
        for (int c = sub; c < DK; c += 16) {
            const double v = (double)Rs[row][c];
            s += v * v;
        }
        s += __shfl_xor(s, 1, 16);
        s += __shfl_xor(s, 2, 16);
        s += __shfl_xor(s, 4, 16);
        s += __shfl_xor(s, 8, 16);
        if (sub == 0) out_norm[m0 + row] = (float)sqrt(s);
    }

    const int tx = tid & 15, ty = tid >> 4;
    const int srow = tid >> 2, s4 = tid & 3;

    for (int nt = 0; nt < 16; ++nt) {
        const int n0 = nt * 64;
        float chn[4] = {0.f, 0.f, 0.f, 0.f}, tot[4] = {0.f, 0.f, 0.f, 0.f};

        for (int kt = 0; kt < 64; ++kt) {
            const int k0 = kt * 16;
            __syncthreads();
            const float4 w = *(const float4*)&Sm[(size_t)(n0 + srow) * DK + k0 + s4 * 4];
            Bsh[s4 * 4 + 0][srow] = w.x;
            Bsh[s4 * 4 + 1][srow] = w.y;
            Bsh[s4 * 4 + 2][srow] = w.z;
            Bsh[s4 * 4 + 3][srow] = w.w;
            __syncthreads();
#pragma unroll
            for (int kk = 0; kk < 16; ++kk) {
                const float a = Rs[ty][k0 + kk];
#pragma unroll
                for (int j = 0; j < 4; ++j)
                    chn[j] = fmaf(a, Bsh[kk][tx * 4 + j], chn[j]);
            }
            if (kt == 31) {
#pragma unroll
                for (int j = 0; j < 4; ++j) { tot[j] += chn[j]; chn[j] = 0.0f; }
            }
        }
#pragma unroll
        for (int j = 0; j < 4; ++j) tot[j] += chn[j];
#pragma unroll
        for (int j = 0; j < 4; ++j)
            out_sign[(size_t)(m0 + ty) * DK + n0 + tx * 4 + j] =
                (tot[j] >= 0.0f) ? 1.0f : -1.0f;
    }
}

extern "C" void kernel_launch(void* const* d_in, const int* in_sizes, int n_in,
                              void* d_out, int out_size, void* d_ws, size_t ws_size,
                              hipStream_t stream)
{
    const float* x    = (const float*)d_in[0];
    const float* Pi   = (const float*)d_in[1];
    const float* S    = (const float*)d_in[2];
    const float* cent = (const float*)d_in[3];
    const float* bnd  = (const float*)d_in[4];

    float* out_idx  = (float*)d_out;
    float* out_sign = out_idx + (size_t)NB * DK;
    float* out_norm = out_idx + 2 * (size_t)NB * DK;

    const dim3 grid(DK / BN, NB / BM);      // (8, 256)
    const size_t needF32 = (size_t)NB * DK * sizeof(float);   // 134 MB

    gk<0><<<grid, 256, 0, stream>>>(x, Pi, (const float*)nullptr, cent, bnd, out_idx);

    if (ws_size >= needF32) {
        float* resid = (float*)d_ws;
        gk<1><<<grid, 256, 0, stream>>>(out_idx, Pi, x, cent, bnd, resid);
        gk<2><<<grid, 256, 0, stream>>>(resid, S, (const float*)nullptr, cent, bnd, out_sign);
        norm_k<<<NB / 4, 256, 0, stream>>>(resid, out_norm);
    } else {
        gk<1><<<grid, 256, 0, stream>>>(out_idx, Pi, x, cent, bnd, out_sign);
        stage2_band<<<NB / 16, 256, 0, stream>>>(out_sign, S, out_sign, out_norm);
    }
}

// Round 14
// 3291.843 us; speedup vs baseline: 14.0499x; 1.0277x over previous
//
#include <hip/hip_runtime.h>

#define DK 1024
#define NB 32768
#define BM 128
#define BN 128
#define BKT 32
#define NKT (DK / BKT)     // 32 k-tiles
#define FLUSH_KT 15        // KC=512 panel boundary (after kt 15)

typedef const __attribute__((address_space(1))) void GAS;
typedef __attribute__((address_space(3))) void LAS;

__device__ __forceinline__ void gll16(const void* g, void* l) {
    __builtin_amdgcn_global_load_lds((GAS*)g, (LAS*)l, 16, 0, 0);
}

// Reference model (probes r4-r8, verified r9-r13): np ref = f32 sgemm, KC=512
// K-panels; per element ascending-k single-accumulator f32 FMA chain per
// panel; panel sums added in order (P0 + P1). DO NOT reorder the chain.
// P0 is parked in `out` at kt==FLUSH_KT and re-read in the epilogue (same
// thread, in-order add -> bit-identical).
//
// r14 structure: A-operand reads are 16-lane broadcasts -> served from
// L1/L2 via direct global float4 loads (no LDS). Only B is staged to LDS
// (DMA global_load_lds, double-buffered). LDS traffic halves vs r13.
// MODE 0: y = x @ Pi^T (NT B) -> idx to out, yhat=cent[idx] to yout
// MODE 1: xhat = yhat @ Pi (NN B) -> resid = x - xhat to out
// MODE 2: p = resid @ S^T (NT B) -> sign to out
template<int MODE>
__global__ __launch_bounds__(256)
void gk(const float* __restrict__ A,
        const float* __restrict__ W,
        const float* __restrict__ X,
        const float* __restrict__ cent,
        const float* __restrict__ bnd,
        float* __restrict__ out,
        float* __restrict__ yout)
{
    __shared__ float Bs[2][BN * BKT];
    __shared__ float centS[8];

    const int tid  = threadIdx.x;
    const int lane = tid & 63;
    const int wid  = tid >> 6;
    const int tx8 = tid & 15, ty8 = tid >> 4;
    const int m0 = blockIdx.y * BM;
    const int n0 = blockIdx.x * BN;

    const int lr = lane >> 3;       // local row within 8-row DMA chunk
    const int gs = lane & 7;        // granule slot within row

    if (MODE == 0 && tid < 8) centS[tid] = cent[tid];

    // NT B tile DMA: [n-row][32k], granule slot g holds data granule g^(row>>3 &7)
    // via pre-swizzled SOURCE address (dest linear). 16 instrs/block.
    auto stageNT = [&](float* dst, const float* src, int kt) {
#pragma unroll
        for (int q = 0; q < 4; ++q) {
            const int rb  = wid * 32 + q * 8;
            const int key = (rb >> 3) & 7;                 // wave-uniform
            const float* gp = src + (size_t)(n0 + rb + lr) * DK
                                  + kt * BKT + ((gs ^ key) << 2);
            gll16(gp, dst + rb * BKT);
        }
    };
    // NN B tile DMA (mode 1): Bs[kk][n], linear.
    auto stageNN = [&](float* dst, const float* src, int kt) {
#pragma unroll
        for (int q = 0; q < 4; ++q) {
            const int r2 = (wid * 4 + q) * 2;
            const float* gp = src + (size_t)(kt * BKT + r2 + (lane >> 5)) * DK
                                  + n0 + ((lane & 31) << 2);
            gll16(gp, dst + r2 * BN);
        }
    };

    const float* aRow = A + (size_t)(m0 + ty8 * 8) * DK;
    const int bkr = tx8 & 7;   // NT read-side XOR key (rows tx8*8+j -> row>>3 = tx8)

    float chn[8][8];
#pragma unroll
    for (int i = 0; i < 8; ++i)
#pragma unroll
        for (int j = 0; j < 8; ++j) chn[i][j] = 0.0f;

    // ---- prologue: stage B tile 0 ----
    if (MODE == 1) stageNN(Bs[0], W, 0); else stageNT(Bs[0], W, 0);
    __syncthreads();                      // drains DMA; centS visible

    int cur = 0;
    for (int kt = 0; kt < NKT; ++kt) {
        if (kt + 1 < NKT) {               // issue next B tile before compute
            if (MODE == 1) stageNN(Bs[cur ^ 1], W, kt + 1);
            else           stageNT(Bs[cur ^ 1], W, kt + 1);
        }

        const float4* Bs4 = (const float4*)Bs[cur];
#pragma unroll
        for (int c = 0; c < 8; ++c) {
            float4 a4[8];                 // A direct from global (L1/L2 broadcast)
#pragma unroll
            for (int i = 0; i < 8; ++i)
                a4[i] = *(const float4*)(aRow + (size_t)i * DK + kt * BKT + c * 4);

            if constexpr (MODE != 1) {
#pragma unroll
                for (int jh = 0; jh < 4; ++jh) {
                    const float4 b0 = Bs4[(tx8 * 8 + jh * 2) * 8 + (c ^ bkr)];
                    const float4 b1 = Bs4[(tx8 * 8 + jh * 2 + 1) * 8 + (c ^ bkr)];
#pragma unroll
                    for (int e = 0; e < 4; ++e) {
                        const float be0 = ((const float*)&b0)[e];
                        const float be1 = ((const float*)&b1)[e];
#pragma unroll
                        for (int i = 0; i < 8; ++i) {
                            const float ae = ((const float*)&a4[i])[e];
                            chn[i][jh * 2]     = fmaf(ae, be0, chn[i][jh * 2]);
                            chn[i][jh * 2 + 1] = fmaf(ae, be1, chn[i][jh * 2 + 1]);
                        }
                    }
                }
            } else {
#pragma unroll
                for (int e = 0; e < 4; ++e) {
                    const float4 b0 = *(const float4*)&Bs[cur][(c * 4 + e) * BN + tx8 * 8];
                    const float4 b1 = *(const float4*)&Bs[cur][(c * 4 + e) * BN + tx8 * 8 + 4];
                    const float b[8] = {b0.x, b0.y, b0.z, b0.w, b1.x, b1.y, b1.z, b1.w};
#pragma unroll
                    for (int i = 0; i < 8; ++i) {
                        const float ae = ((const float*)&a4[i])[e];
#pragma unroll
                        for (int j = 0; j < 8; ++j)
                            chn[i][j] = fmaf(ae, b[j], chn[i][j]);
                    }
                }
            }
        }

        // ---- KC=512 panel flush: park P0 in out, restart chain ----
        if (kt == FLUSH_KT) {
#pragma unroll
            for (int i = 0; i < 8; ++i) {
                const int row = m0 + ty8 * 8 + i;
#pragma unroll
                for (int jq = 0; jq < 2; ++jq) {
                    float4 v;
                    v.x = chn[i][jq * 4 + 0];
                    v.y = chn[i][jq * 4 + 1];
                    v.z = chn[i][jq * 4 + 2];
                    v.w = chn[i][jq * 4 + 3];
                    *(float4*)&out[(size_t)row * DK + n0 + tx8 * 8 + jq * 4] = v;
                    chn[i][jq * 4 + 0] = 0.0f;
                    chn[i][jq * 4 + 1] = 0.0f;
                    chn[i][jq * 4 + 2] = 0.0f;
                    chn[i][jq * 4 + 3] = 0.0f;
                }
            }
        }

        __syncthreads();     // drains DMA; next B buffer ready
        cur ^= 1;
    }

    // ---- epilogue: tot = P0(from out) + P1(chn), in order ----
    if constexpr (MODE == 0) {
        float bb[7];
#pragma unroll
        for (int t = 0; t < 7; ++t) bb[t] = bnd[t];
#pragma unroll
        for (int i = 0; i < 8; ++i) {
            const int row = m0 + ty8 * 8 + i;
#pragma unroll
            for (int jq = 0; jq < 2; ++jq) {
                const int col = n0 + tx8 * 8 + jq * 4;
                const float4 p = *(const float4*)&out[(size_t)row * DK + col];
                float4 v, yv;
#pragma unroll
                for (int e = 0; e < 4; ++e) {
                    const float yf = ((const float*)&p)[e] + chn[i][jq * 4 + e];
                    int id = 0;
#pragma unroll
                    for (int t = 0; t < 7; ++t) id += (yf > bb[t]) ? 1 : 0;
                    ((float*)&v)[e]  = (float)id;
                    ((float*)&yv)[e] = centS[id];
                }
                *(float4*)&out[(size_t)row * DK + col]  = v;
                *(float4*)&yout[(size_t)row * DK + col] = yv;
            }
        }
    } else if constexpr (MODE == 1) {
#pragma unroll
        for (int i = 0; i < 8; ++i) {
            const int row = m0 + ty8 * 8 + i;
#pragma unroll
            for (int jq = 0; jq < 2; ++jq) {
                const int col = n0 + tx8 * 8 + jq * 4;
                const float4 p  = *(const float4*)&out[(size_t)row * DK + col];
                const float4 xv = *(const float4*)&X[(size_t)row * DK + col];
                float4 v;
                v.x = xv.x - (p.x + chn[i][jq * 4 + 0]);
                v.y = xv.y - (p.y + chn[i][jq * 4 + 1]);
                v.z = xv.z - (p.z + chn[i][jq * 4 + 2]);
                v.w = xv.w - (p.w + chn[i][jq * 4 + 3]);
                *(float4*)&out[(size_t)row * DK + col] = v;
            }
        }
    } else {
#pragma unroll
        for (int i = 0; i < 8; ++i) {
            const int row = m0 + ty8 * 8 + i;
#pragma unroll
            for (int jq = 0; jq < 2; ++jq) {
                const int col = n0 + tx8 * 8 + jq * 4;
                const float4 p = *(const float4*)&out[(size_t)row * DK + col];
                float4 v;
#pragma unroll
                for (int e = 0; e < 4; ++e)
                    ((float*)&v)[e] =
                        ((((const float*)&p)[e] + chn[i][jq * 4 + e]) >= 0.0f)
                            ? 1.0f : -1.0f;
                *(float4*)&out[(size_t)row * DK + col] = v;
            }
        }
    }
}

// Fallback mode-1 (LUT-based, r13-verbatim): used when ws is small, so that
// resid can live in out_sign without the yhat buffer (avoids cross-block race).
__global__ __launch_bounds__(256)
void gk1_lut(const float* __restrict__ IDXF,
             const float* __restrict__ W,
             const float* __restrict__ X,
             const float* __restrict__ cent,
             float* __restrict__ out)
{
    __shared__ float As[2][BM * BKT];
    __shared__ float Bs[2][BN * BKT];
    __shared__ float centS[8];

    const int tid  = threadIdx.x;
    const int lane = tid & 63;
    const int wid  = tid >> 6;
    const int tx8 = tid & 15, ty8 = tid >> 4;
    const int m0 = blockIdx.y * BM;
    const int n0 = blockIdx.x * BN;

    const int arow = tid >> 1;
    const int ah   = (tid & 1) * 4;
    const int akey = (arow >> 3) & 7;
    float4 pidx[4];

    if (tid < 8) centS[tid] = cent[tid];

    auto stageNN = [&](float* dst, const float* src, int kt) {
#pragma unroll
        for (int q = 0; q < 4; ++q) {
            const int r2 = (wid * 4 + q) * 2;
            const float* gp = src + (size_t)(kt * BKT + r2 + (lane >> 5)) * DK
                                  + n0 + ((lane & 31) << 2);
            gll16(gp, dst + r2 * BN);
        }
    };
    auto loadIdx = [&](int kt) {
#pragma unroll
        for (int g = 0; g < 4; ++g)
            pidx[g] = *(const float4*)&IDXF[(size_t)(m0 + arow) * DK + kt * BKT + (ah + g) * 4];
    };
    auto writeA = [&](float* dst) {
#pragma unroll
        for (int g = 0; g < 4; ++g) {
            float4 v;
            v.x = centS[(int)pidx[g].x];
            v.y = centS[(int)pidx[g].y];
            v.z = centS[(int)pidx[g].z];
            v.w = centS[(int)pidx[g].w];
            *(float4*)&dst[arow * BKT + (((ah + g) ^ akey) << 2)] = v;
        }
    };

    float chn[8][8];
#pragma unroll
    for (int i = 0; i < 8; ++i)
#pragma unroll
        for (int j = 0; j < 8; ++j) chn[i][j] = 0.0f;

    const int akr = ty8 & 7;

    loadIdx(0); stageNN(Bs[0], W, 0);
    __syncthreads();
    writeA(As[0]); __syncthreads();

    int cur = 0;
    for (int kt = 0; kt < NKT; ++kt) {
        if (kt + 1 < NKT) { loadIdx(kt + 1); stageNN(Bs[cur ^ 1], W, kt + 1); }

        const float4* As4 = (const float4*)As[cur];
#pragma unroll
        for (int c = 0; c < 8; ++c) {
            float4 a4[8];
#pragma unroll
            for (int i = 0; i < 8; ++i)
                a4[i] = As4[(ty8 * 8 + i) * 8 + (c ^ akr)];
#pragma unroll
            for (int e = 0; e < 4; ++e) {
                const float4 b0 = *(const float4*)&Bs[cur][(c * 4 + e) * BN + tx8 * 8];
                const float4 b1 = *(const float4*)&Bs[cur][(c * 4 + e) * BN + tx8 * 8 + 4];
                const float b[8] = {b0.x, b0.y, b0.z, b0.w, b1.x, b1.y, b1.z, b1.w};
#pragma unroll
                for (int i = 0; i < 8; ++i) {
                    const float ae = ((const float*)&a4[i])[e];
#pragma unroll
                    for (int j = 0; j < 8; ++j)
                        chn[i][j] = fmaf(ae, b[j], chn[i][j]);
                }
            }
        }

        if (kt == FLUSH_KT) {
#pragma unroll
            for (int i = 0; i < 8; ++i) {
                const int row = m0 + ty8 * 8 + i;
#pragma unroll
                for (int jq = 0; jq < 2; ++jq) {
                    float4 v;
                    v.x = chn[i][jq * 4 + 0];
                    v.y = chn[i][jq * 4 + 1];
                    v.z = chn[i][jq * 4 + 2];
                    v.w = chn[i][jq * 4 + 3];
                    *(float4*)&out[(size_t)row * DK + n0 + tx8 * 8 + jq * 4] = v;
                    chn[i][jq * 4 + 0] = 0.0f;
                    chn[i][jq * 4 + 1] = 0.0f;
                    chn[i][jq * 4 + 2] = 0.0f;
                    chn[i][jq * 4 + 3] = 0.0f;
                }
            }
        }

        if (kt + 1 < NKT) writeA(As[cur ^ 1]);
        __syncthreads();
        cur ^= 1;
    }

#pragma unroll
    for (int i = 0; i < 8; ++i) {
        const int row = m0 + ty8 * 8 + i;
#pragma unroll
        for (int jq = 0; jq < 2; ++jq) {
            const int col = n0 + tx8 * 8 + jq * 4;
            const float4 p  = *(const float4*)&out[(size_t)row * DK + col];
            const float4 xv = *(const float4*)&X[(size_t)row * DK + col];
            float4 v;
            v.x = xv.x - (p.x + chn[i][jq * 4 + 0]);
            v.y = xv.y - (p.y + chn[i][jq * 4 + 1]);
            v.z = xv.z - (p.z + chn[i][jq * 4 + 2]);
            v.w = xv.w - (p.w + chn[i][jq * 4 + 3]);
            *(float4*)&out[(size_t)row * DK + col] = v;
        }
    }
}

__global__ __launch_bounds__(256)
void norm_k(const float* __restrict__ resid, float* __restrict__ outn)
{
    const int lane = threadIdx.x & 63;
    const int row  = blockIdx.x * 4 + (threadIdx.x >> 6);
    const float* r = &resid[(size_t)row * DK];
    double s = 0.0;
    for (int i = lane; i < DK; i += 64) {
        const double v = (double)r[i];
        s += v * v;
    }
#pragma unroll
    for (int off = 32; off > 0; off >>= 1)
        s += __shfl_xor(s, off, 64);
    if (lane == 0) outn[row] = (float)sqrt(s);
}

__global__ __launch_bounds__(256)
void stage2_band(const float* __restrict__ RS,
                 const float* __restrict__ Sm,
                 float* __restrict__ out_sign,
                 float* __restrict__ out_norm)
{
    __shared__ float Rs[16][DK + 1];
    __shared__ float Bsh[16][64];

    const int tid = threadIdx.x;
    const int m0  = blockIdx.x * 16;

    for (int c = tid; c < 16 * 256; c += 256) {
        const int row = c >> 8, q = c & 255;
        const float4 v = *(const float4*)&RS[(size_t)(m0 + row) * DK + q * 4];
        Rs[row][q * 4 + 0] = v.x;
        Rs[row][q * 4 + 1] = v.y;
        Rs[row][q * 4 + 2] = v.z;
        Rs[row][q * 4 + 3] = v.w;
    }
    __syncthreads();

    {
        const int row = tid >> 4, sub = tid & 15;
        double s = 0.0;
        for (int c = sub; c < DK; c += 16) {
            const double v = (double)Rs[row][c];
            s += v * v;
        }
        s += __shfl_xor(s, 1, 16);
        s += __shfl_xor(s, 2, 16);
        s += __shfl_xor(s, 4, 16);
        s += __shfl_xor(s, 8, 16);
        if (sub == 0) out_norm[m0 + row] = (float)sqrt(s);
    }

    const int tx = tid & 15, ty = tid >> 4;
    const int srow = tid >> 2, s4 = tid & 3;

    for (int nt = 0; nt < 16; ++nt) {
        const int n0 = nt * 64;
        float chn[4] = {0.f, 0.f, 0.f, 0.f}, tot[4] = {0.f, 0.f, 0.f, 0.f};

        for (int kt = 0; kt < 64; ++kt) {
            const int k0 = kt * 16;
            __syncthreads();
            const float4 w = *(const float4*)&Sm[(size_t)(n0 + srow) * DK + k0 + s4 * 4];
            Bsh[s4 * 4 + 0][srow] = w.x;
            Bsh[s4 * 4 + 1][srow] = w.y;
            Bsh[s4 * 4 + 2][srow] = w.z;
            Bsh[s4 * 4 + 3][srow] = w.w;
            __syncthreads();
#pragma unroll
            for (int kk = 0; kk < 16; ++kk) {
                const float a = Rs[ty][k0 + kk];
#pragma unroll
                for (int j = 0; j < 4; ++j)
                    chn[j] = fmaf(a, Bsh[kk][tx * 4 + j], chn[j]);
            }
            if (kt == 31) {
#pragma unroll
                for (int j = 0; j < 4; ++j) { tot[j] += chn[j]; chn[j] = 0.0f; }
            }
        }
#pragma unroll
        for (int j = 0; j < 4; ++j) tot[j] += chn[j];
#pragma unroll
        for (int j = 0; j < 4; ++j)
            out_sign[(size_t)(m0 + ty) * DK + n0 + tx * 4 + j] =
                (tot[j] >= 0.0f) ? 1.0f : -1.0f;
    }
}

extern "C" void kernel_launch(void* const* d_in, const int* in_sizes, int n_in,
                              void* d_out, int out_size, void* d_ws, size_t ws_size,
                              hipStream_t stream)
{
    const float* x    = (const float*)d_in[0];
    const float* Pi   = (const float*)d_in[1];
    const float* S    = (const float*)d_in[2];
    const float* cent = (const float*)d_in[3];
    const float* bnd  = (const float*)d_in[4];

    float* out_idx  = (float*)d_out;
    float* out_sign = out_idx + (size_t)NB * DK;
    float* out_norm = out_idx + 2 * (size_t)NB * DK;

    const dim3 grid(DK / BN, NB / BM);      // (8, 256)
    const size_t needF32 = (size_t)NB * DK * sizeof(float);   // 134 MB

    // mode 0: idx -> out_idx, yhat -> out_sign (overwritten later by signs)
    gk<0><<<grid, 256, 0, stream>>>(x, Pi, (const float*)nullptr, cent, bnd,
                                    out_idx, out_sign);

    if (ws_size >= needF32) {
        float* resid = (float*)d_ws;
        gk<1><<<grid, 256, 0, stream>>>(out_sign /*A=yhat*/, Pi, x, cent, bnd,
                                        resid, (float*)nullptr);
        gk<2><<<grid, 256, 0, stream>>>(resid, S, (const float*)nullptr, cent, bnd,
                                        out_sign, (float*)nullptr);
        norm_k<<<NB / 4, 256, 0, stream>>>(resid, out_norm);
    } else {
        gk1_lut<<<grid, 256, 0, stream>>>(out_idx, Pi, x, cent, out_sign);
        stage2_band<<<NB / 16, 256, 0, stream>>>(out_sign, S, out_sign, out_norm);
    }
}